// Round 1
// baseline (525.424 us; speedup 1.0000x reference)
//
#include <hip/hip_runtime.h>

#define BB 256
#define TT 1024
#define VV 64
#define LL 64
#define NEGF (-1e30f)

__device__ __forceinline__ int   f2i(float x) { return __float_as_int(x); }
__device__ __forceinline__ float i2f(int x)   { return __int_as_float(x); }

// DPP-based partial add: x += dpp_move(x); invalid lanes contribute 0
template <int CTRL>
__device__ __forceinline__ float dpp_add(float x) {
  int y = __builtin_amdgcn_update_dpp(0, f2i(x), CTRL, 0xF, 0xF, true);
  return x + i2f(y);
}

// full 64-lane sum, result broadcast via readlane(63)
__device__ __forceinline__ float wave_sum63(float x) {
  x = dpp_add<0x111>(x);  // row_shr:1
  x = dpp_add<0x112>(x);  // row_shr:2
  x = dpp_add<0x114>(x);  // row_shr:4
  x = dpp_add<0x118>(x);  // row_shr:8
  x = dpp_add<0x142>(x);  // row_bcast:15
  x = dpp_add<0x143>(x);  // row_bcast:31
  return i2f(__builtin_amdgcn_readlane(f2i(x), 63));
}

__device__ __forceinline__ float lae2(float a, float b) {
  float m = fmaxf(a, b);
  float d = fminf(a, b) - m;          // 0 if both equal (incl. both NEGF)
  return m + __logf(1.0f + __expf(d));
}

extern "C" __global__ void __launch_bounds__(64)
ctc_fused(const int* __restrict__ labels, const float* __restrict__ logits,
          const int* __restrict__ mask, float* __restrict__ out) {
  const int b = blockIdx.x;
  const int lane = threadIdx.x;

  // labels: [B, L] int32; label for extended state s=2*lane+1
  const int lab = labels[b * LL + lane];
  const int lab_len = (int)__popcll(__ballot(lab != 0));

  // logits_len = sum of prefix-True mask row
  int lsum = 0;
  const int* mrow = mask + b * TT;
#pragma unroll
  for (int k = 0; k < TT / 64; ++k) lsum += mrow[lane + (k << 6)];
#pragma unroll
  for (int off = 32; off; off >>= 1) lsum += __shfl_xor(lsum, off);
  int len = __builtin_amdgcn_readfirstlane(lsum);
  len = len < 1 ? 1 : (len > TT ? TT : len);

  // allow_skip for odd state 2*lane+1: lab != 0 && lab != prev_lab
  const int plab = __builtin_amdgcn_update_dpp(0, lab, 0x138, 0xF, 0xF, false); // wave_shr:1, lane0 -> 0
  const bool skip_ok = (lab != 0) && (lab != plab);
  const int lab4 = (lab & 63) << 2;

  const float* lg = logits + (size_t)b * TT * VV + lane;

  // prefetch ring, depth 8 (256B coalesced per step)
  float xbuf[8];
#pragma unroll
  for (int u = 0; u < 8; ++u) xbuf[u] = lg[u * VV];

  float sumLse = 0.0f;
  float a0, a1, a2;  // alpha'[2*lane], alpha'[2*lane+1], alpha'[128] (lane63)

  // ---- t = 0: init ----
  {
    float x = xbuf[0];
    xbuf[0] = lg[8 * VV];
    sumLse += __logf(wave_sum63(__expf(x)));
    const float x0 = i2f(__builtin_amdgcn_readlane(f2i(x), 0));
    const float xl = i2f(__builtin_amdgcn_ds_bpermute(lab4, f2i(x)));
    a0 = (lane == 0) ? x0 : NEGF;
    a1 = (lane == 0) ? xl : NEGF;
    a2 = NEGF;
  }

  // ---- t = 1 .. len-1 ----
  for (int tb = 1; tb < len; tb += 8) {
#pragma unroll
    for (int u = 0; u < 8; ++u) {
      const int t = tb + u;
      if (t >= len) break;                 // wave-uniform
      const int slot = (1 + u) & 7;        // == t & 7 (tb % 8 == 1)
      float x = xbuf[slot];
      int pf = t + 8;
      pf = pf > TT - 1 ? TT - 1 : pf;
      xbuf[slot] = lg[(size_t)pf * VV];

      // deferred softmax: accumulate lse (off the DP critical path)
      sumLse += __logf(wave_sum63(__expf(x)));

      const float x0 = i2f(__builtin_amdgcn_readlane(f2i(x), 0));            // blank logit
      const float xl = i2f(__builtin_amdgcn_ds_bpermute(lab4, f2i(x)));      // label logit

      // alpha[s-1] for even state: neighbor's a1 (wave_shr:1, lane0 -> NEGF)
      const float a1p =
          i2f(__builtin_amdgcn_update_dpp(f2i(NEGF), f2i(a1), 0x138, 0xF, 0xF, false));

      // shared-max 3-term logaddexp
      const float m  = fmaxf(fmaxf(a0, a1), a1p);
      const float E0 = __expf(a0 - m);
      const float E1 = __expf(a1 - m);
      const float Ep = __expf(a1p - m);
      float na0 = x0 + m + __logf(E0 + Ep);                                  // s even
      float na1 = xl + m + __logf(E0 + E1 + (skip_ok ? Ep : 0.0f));          // s odd
      float na2 = x0 + lae2(a2, a1);                                         // s = 128 (lane63)
      na0 = fmaxf(na0, NEGF);  // kill -inf from underflow (dead mass)
      na1 = fmaxf(na1, NEGF);
      a0 = na0; a1 = na1; a2 = na2;
    }
  }

  // ---- epilogue: loss_b = sumLse - logaddexp(alpha'[e], alpha'[e-1]), e = 2*lab_len ----
  float ae, ae1;
  if (lab_len >= LL) {            // e = 128
    ae  = i2f(__builtin_amdgcn_readlane(f2i(a2), 63));
    ae1 = i2f(__builtin_amdgcn_readlane(f2i(a1), 63));
  } else if (lab_len >= 1) {      // e = 2*lab_len (even -> a0 of lane lab_len)
    ae  = i2f(__builtin_amdgcn_readlane(f2i(a0), lab_len));
    ae1 = i2f(__builtin_amdgcn_readlane(f2i(a1), lab_len - 1));
  } else {                        // e = 0; ref reads alpha[0] twice
    ae  = i2f(__builtin_amdgcn_readlane(f2i(a0), 0));
    ae1 = ae;
  }
  float loss = sumLse - lae2(ae, ae1);
  if (lab_len > len) loss = 0.0f;  // feasibility mask
  if (lane == 0) atomicAdd(out, loss * (1.0f / 256.0f));
}

extern "C" void kernel_launch(void* const* d_in, const int* in_sizes, int n_in,
                              void* d_out, int out_size, void* d_ws, size_t ws_size,
                              hipStream_t stream) {
  (void)in_sizes; (void)n_in; (void)out_size; (void)d_ws; (void)ws_size;
  hipMemsetAsync(d_out, 0, sizeof(float), stream);  // d_out is poisoned 0xAA
  ctc_fused<<<dim3(BB), dim3(64), 0, stream>>>(
      (const int*)d_in[0], (const float*)d_in[1], (const int*)d_in[2], (float*)d_out);
}

// Round 2
// 472.926 us; speedup vs baseline: 1.1110x; 1.1110x over previous
//
#include <hip/hip_runtime.h>

#define BB 256
#define TT 1024
#define VV 64
#define LL 64
#define NEGF (-1e30f)
#define WS_STRIDE 16   // floats per batch element in d_ws (cache-line spacing)

__device__ __forceinline__ int   f2i(float x) { return __float_as_int(x); }
__device__ __forceinline__ float i2f(int x)   { return __int_as_float(x); }

__device__ __forceinline__ float lae2(float a, float b) {
  float m = fmaxf(a, b);
  float d = fminf(a, b) - m;          // 0 if both equal (incl. both NEGF)
  return m + __logf(1.0f + __expf(d));
}

// ---------- Phase 1: sum of log-sum-exp over valid t, per batch element ----------
// grid: B * (T/64) blocks of 256 threads. Each block: 64 t-rows of one b.
// Wave w handles rows [w*16, w*16+16) in 4 passes; 16 lanes x float4 per row.
extern "C" __global__ void __launch_bounds__(256)
ctc_lse(const float* __restrict__ logits, const int* __restrict__ mask,
        float* __restrict__ sums) {
  const int bid = blockIdx.x;
  const int b   = bid >> 4;            // T/64 = 16 blocks per b
  const int tb  = (bid & 15) << 6;     // first t-row of this block
  const int tid = threadIdx.x;
  const int lane = tid & 63;
  const int w    = tid >> 6;

  const float* lg = logits + (size_t)b * TT * VV;
  const int colv = (lane & 15) << 2;

  float acc = 0.0f;
#pragma unroll
  for (int p = 0; p < 4; ++p) {
    const int rowT = tb + (w << 4) + (p << 2) + (lane >> 4);
    const float4 v = *(const float4*)(lg + (size_t)rowT * VV + colv);
    float s = __expf(v.x) + __expf(v.y) + __expf(v.z) + __expf(v.w);
    s += __shfl_xor(s, 1);
    s += __shfl_xor(s, 2);
    s += __shfl_xor(s, 4);
    s += __shfl_xor(s, 8);             // 16-lane group sum -> row LSE argument
    if ((lane & 15) == 0) {
      const int mv = mask[b * TT + rowT];   // prefix-true: mv!=0 <=> t < len
      acc += mv ? __logf(s) : 0.0f;
    }
  }
  acc = ((lane & 15) == 0) ? acc : 0.0f;
  acc += __shfl_xor(acc, 16);
  acc += __shfl_xor(acc, 32);
  if (lane == 0) atomicAdd(sums + b * WS_STRIDE, acc);
}

// ---------- Phase 2: the sequential alpha DP on RAW logits ----------
// One wave per batch element. Lane l holds alpha'[2l] (a0) and alpha'[2l+1] (a1);
// lane 63 additionally tracks alpha'[128] (a2). Gather addresses are t-invariant
// per lane -> direct global loads, prefetched 16 deep. No LDS, no bpermute.
extern "C" __global__ void __launch_bounds__(64)
ctc_dp(const int* __restrict__ labels, const float* __restrict__ logits,
       const int* __restrict__ mask, const float* __restrict__ sums,
       float* __restrict__ out) {
  const int b = blockIdx.x;
  const int lane = threadIdx.x;

  const int lab = labels[b * LL + lane];                 // label for state 2*lane+1
  const int lab_len = (int)__popcll(__ballot(lab != 0));

  // logits_len = popcount of prefix-true mask row
  int lsum = 0;
  const int* mrow = mask + b * TT;
#pragma unroll
  for (int k = 0; k < TT / 64; ++k) lsum += mrow[lane + (k << 6)];
#pragma unroll
  for (int off = 32; off; off >>= 1) lsum += __shfl_xor(lsum, off);
  int len = __builtin_amdgcn_readfirstlane(lsum);
  len = len < 1 ? 1 : (len > TT ? TT : len);

  // allow_skip for odd state: lab != 0 && lab != prev lab
  const int plab = __builtin_amdgcn_update_dpp(0, lab, 0x138, 0xF, 0xF, false); // wave_shr:1
  const bool skip_ok = (lab != 0) && (lab != plab);

  const float* lg   = logits + (size_t)b * TT * VV;
  const float* glab = lg + (lab & 63);                   // per-lane gather base

  // prefetch rings, depth 16
  float xg[16], xb[16];
#pragma unroll
  for (int u = 0; u < 16; ++u) { xg[u] = glab[u * VV]; xb[u] = lg[u * VV]; }

  float a0, a1, a2;

  // ---- t = 0 ----
  {
    const float x0 = xb[0];                              // blank logit (uniform)
    const float xl = xg[0];                              // label logit (per lane)
    xg[0] = glab[16 * VV];
    xb[0] = lg[16 * VV];
    a0 = (lane == 0) ? x0 : NEGF;
    a1 = (lane == 0) ? xl : NEGF;
    a2 = NEGF;
  }

  // ---- t = 1 .. len-1 ----
  for (int tb_ = 1; tb_ < len; tb_ += 16) {
#pragma unroll
    for (int u = 0; u < 16; ++u) {
      const int t = tb_ + u;
      if (t >= len) break;                               // wave-uniform
      const int slot = (1 + u) & 15;                     // == t & 15
      const float x0 = xb[slot];
      const float xl = xg[slot];
      int pf = t + 16;
      pf = pf > TT - 1 ? TT - 1 : pf;
      xg[slot] = glab[(size_t)pf * VV];
      xb[slot] = lg[(size_t)pf * VV];

      // alpha[s-1] for even state s=2l: neighbor's a1 (wave_shr:1, lane0 -> NEGF)
      const float a1p =
          i2f(__builtin_amdgcn_update_dpp(f2i(NEGF), f2i(a1), 0x138, 0xF, 0xF, false));

      // shared-max 3-term logaddexp
      const float m  = fmaxf(fmaxf(a0, a1), a1p);
      const float E0 = __expf(a0 - m);
      const float E1 = __expf(a1 - m);
      const float Ep = __expf(a1p - m);
      float na0 = x0 + m + __logf(E0 + Ep);                           // even state
      float na1 = xl + m + __logf(E0 + E1 + (skip_ok ? Ep : 0.0f));   // odd state
      float na2 = x0 + lae2(a2, a1);                                  // state 128 (lane63)
      na0 = fmaxf(na0, NEGF);
      na1 = fmaxf(na1, NEGF);
      a0 = na0; a1 = na1; a2 = na2;
    }
  }

  // ---- epilogue ----
  float ae, ae1;
  if (lab_len >= LL) {            // e = 128
    ae  = i2f(__builtin_amdgcn_readlane(f2i(a2), 63));
    ae1 = i2f(__builtin_amdgcn_readlane(f2i(a1), 63));
  } else if (lab_len >= 1) {      // e = 2*lab_len
    ae  = i2f(__builtin_amdgcn_readlane(f2i(a0), lab_len));
    ae1 = i2f(__builtin_amdgcn_readlane(f2i(a1), lab_len - 1));
  } else {
    ae  = i2f(__builtin_amdgcn_readlane(f2i(a0), 0));
    ae1 = ae;
  }
  float loss = sums[b * WS_STRIDE] - lae2(ae, ae1);
  if (lab_len > len) loss = 0.0f;
  if (lane == 0) atomicAdd(out, loss * (1.0f / 256.0f));
}

extern "C" void kernel_launch(void* const* d_in, const int* in_sizes, int n_in,
                              void* d_out, int out_size, void* d_ws, size_t ws_size,
                              hipStream_t stream) {
  (void)in_sizes; (void)n_in; (void)out_size; (void)ws_size;
  const int* labels = (const int*)d_in[0];
  const float* logits = (const float*)d_in[1];
  const int* mask = (const int*)d_in[2];
  float* sums = (float*)d_ws;

  hipMemsetAsync(d_out, 0, sizeof(float), stream);               // poisoned 0xAA
  hipMemsetAsync(sums, 0, BB * WS_STRIDE * sizeof(float), stream);

  ctc_lse<<<dim3(BB * (TT / 64)), dim3(256), 0, stream>>>(logits, mask, sums);
  ctc_dp<<<dim3(BB), dim3(64), 0, stream>>>(labels, logits, mask, sums, (float*)d_out);
}

// Round 3
// 335.245 us; speedup vs baseline: 1.5673x; 1.4107x over previous
//
#include <hip/hip_runtime.h>

#define BB 256
#define TT 1024
#define VV 64
#define LL 64
#define NEGF (-1e30f)
#define WS_STRIDE 16   // floats per batch element in d_ws (cache-line spacing)

__device__ __forceinline__ int   f2i(float x) { return __float_as_int(x); }
__device__ __forceinline__ float i2f(int x)   { return __int_as_float(x); }

__device__ __forceinline__ float lae2(float a, float b) {
  float m = fmaxf(a, b);
  float d = fminf(a, b) - m;          // 0 if both equal (incl. both NEGF)
  return m + __logf(1.0f + __expf(d));
}

// ---------- Phase 1: sum of log-sum-exp over valid t, per batch element ----------
extern "C" __global__ void __launch_bounds__(256)
ctc_lse(const float* __restrict__ logits, const int* __restrict__ mask,
        float* __restrict__ sums) {
  const int bid = blockIdx.x;
  const int b   = bid >> 4;            // T/64 = 16 blocks per b
  const int tb  = (bid & 15) << 6;     // first t-row of this block
  const int tid = threadIdx.x;
  const int lane = tid & 63;
  const int w    = tid >> 6;

  const float* lg = logits + (size_t)b * TT * VV;
  const int colv = (lane & 15) << 2;

  float acc = 0.0f;
#pragma unroll
  for (int p = 0; p < 4; ++p) {
    const int rowT = tb + (w << 4) + (p << 2) + (lane >> 4);
    const float4 v = *(const float4*)(lg + (size_t)rowT * VV + colv);
    float s = __expf(v.x) + __expf(v.y) + __expf(v.z) + __expf(v.w);
    s += __shfl_xor(s, 1);
    s += __shfl_xor(s, 2);
    s += __shfl_xor(s, 4);
    s += __shfl_xor(s, 8);             // 16-lane group sum -> row LSE argument
    if ((lane & 15) == 0) {
      const int mv = mask[b * TT + rowT];   // prefix-true: mv!=0 <=> t < len
      acc += mv ? __logf(s) : 0.0f;
    }
  }
  acc = ((lane & 15) == 0) ? acc : 0.0f;
  acc += __shfl_xor(acc, 16);
  acc += __shfl_xor(acc, 32);
  if (lane == 0) atomicAdd(sums + b * WS_STRIDE, acc);
}

// ---------- Phase 2: sequential alpha DP on RAW logits ----------
// One wave per b. Lane l holds alpha'[2l] (a0), alpha'[2l+1] (a1); lane63 also
// alpha'[128] (a2). Branch-free 16-step blocks: freeze via cndmask (act = t<len)
// so the unroll is guaranteed and the prefetch rings live in VGPRs.
extern "C" __global__ void __launch_bounds__(64)
ctc_dp(const int* __restrict__ labels, const float* __restrict__ logits,
       const int* __restrict__ mask, const float* __restrict__ sums,
       float* __restrict__ out) {
  const int b = blockIdx.x;
  const int lane = threadIdx.x;

  const int lab = labels[b * LL + lane];                 // label for state 2*lane+1
  const int lab_len = (int)__popcll(__ballot(lab != 0));

  // logits_len = popcount of prefix-true mask row
  int lsum = 0;
  const int* mrow = mask + b * TT;
#pragma unroll
  for (int k = 0; k < TT / 64; ++k) lsum += mrow[lane + (k << 6)];
#pragma unroll
  for (int off = 32; off; off >>= 1) lsum += __shfl_xor(lsum, off);
  int len = __builtin_amdgcn_readfirstlane(lsum);
  len = len < 1 ? 1 : (len > TT ? TT : len);

  // allow_skip for odd state: lab != 0 && lab != prev lab
  const int plab = __builtin_amdgcn_update_dpp(0, lab, 0x138, 0xF, 0xF, false); // wave_shr:1
  const bool skip_ok = (lab != 0) && (lab != plab);

  const float* lg   = logits + (size_t)b * TT * VV;
  const float* glab = lg + (lab & 63);                   // per-lane gather base

  // prefetch rings, depth 16, held in VGPRs (no breaks in unrolled bodies!)
  float xg[16], xb[16];
#pragma unroll
  for (int u = 0; u < 16; ++u) { xg[u] = glab[u * VV]; xb[u] = lg[u * VV]; }

  float a0, a1, a2;

  // ---- t = 0 ----
  {
    const float x0 = xb[0];                              // blank logit (uniform)
    const float xl = xg[0];                              // label logit (per lane)
    xg[0] = glab[16 * VV];
    xb[0] = lg[16 * VV];
    a0 = (lane == 0) ? x0 : NEGF;
    a1 = (lane == 0) ? xl : NEGF;
    a2 = NEGF;
  }

  // ---- t = 1 .. len-1, in unconditional 16-step blocks ----
  for (int tb_ = 1; tb_ < len; tb_ += 16) {
#pragma unroll
    for (int u = 0; u < 16; ++u) {
      const int t = tb_ + u;
      const int slot = (1 + u) & 15;                     // == t & 15
      const float x0 = xb[slot];
      const float xl = xg[slot];
      int pf = t + 16;
      pf = pf > TT - 1 ? TT - 1 : pf;
      xg[slot] = glab[(size_t)pf * VV];
      xb[slot] = lg[(size_t)pf * VV];

      // alpha[s-1] for even state s=2l: neighbor's a1 (wave_shr:1, lane0 -> NEGF)
      const float a1p =
          i2f(__builtin_amdgcn_update_dpp(f2i(NEGF), f2i(a1), 0x138, 0xF, 0xF, false));

      // shared-max 3-term logaddexp
      const float m  = fmaxf(fmaxf(a0, a1), a1p);
      const float E0 = __expf(a0 - m);
      const float E1 = __expf(a1 - m);
      const float Ep = __expf(a1p - m);
      float na0 = x0 + m + __logf(E0 + Ep);                           // even state
      float na1 = xl + m + __logf(E0 + E1 + (skip_ok ? Ep : 0.0f));   // odd state
      float na2 = x0 + lae2(a2, a1);                                  // state 128 (lane63)
      na0 = fmaxf(na0, NEGF);
      na1 = fmaxf(na1, NEGF);

      const bool act = t < len;                          // freeze past logits_len
      a0 = act ? na0 : a0;
      a1 = act ? na1 : a1;
      a2 = act ? na2 : a2;
    }
  }

  // ---- epilogue ----
  float ae, ae1;
  if (lab_len >= LL) {            // e = 128
    ae  = i2f(__builtin_amdgcn_readlane(f2i(a2), 63));
    ae1 = i2f(__builtin_amdgcn_readlane(f2i(a1), 63));
  } else if (lab_len >= 1) {      // e = 2*lab_len
    ae  = i2f(__builtin_amdgcn_readlane(f2i(a0), lab_len));
    ae1 = i2f(__builtin_amdgcn_readlane(f2i(a1), lab_len - 1));
  } else {
    ae  = i2f(__builtin_amdgcn_readlane(f2i(a0), 0));
    ae1 = ae;
  }
  float loss = sums[b * WS_STRIDE] - lae2(ae, ae1);
  if (lab_len > len) loss = 0.0f;
  if (lane == 0) atomicAdd(out, loss * (1.0f / 256.0f));
}

extern "C" void kernel_launch(void* const* d_in, const int* in_sizes, int n_in,
                              void* d_out, int out_size, void* d_ws, size_t ws_size,
                              hipStream_t stream) {
  (void)in_sizes; (void)n_in; (void)out_size; (void)ws_size;
  const int* labels = (const int*)d_in[0];
  const float* logits = (const float*)d_in[1];
  const int* mask = (const int*)d_in[2];
  float* sums = (float*)d_ws;

  hipMemsetAsync(d_out, 0, sizeof(float), stream);               // poisoned 0xAA
  hipMemsetAsync(sums, 0, BB * WS_STRIDE * sizeof(float), stream);

  ctc_lse<<<dim3(BB * (TT / 64)), dim3(256), 0, stream>>>(logits, mask, sums);
  ctc_dp<<<dim3(BB), dim3(64), 0, stream>>>(labels, logits, mask, sums, (float*)d_out);
}

// Round 4
// 201.172 us; speedup vs baseline: 2.6118x; 1.6665x over previous
//
#include <hip/hip_runtime.h>

#define BB 256
#define TT 1024
#define VV 64
#define LL 64
#define NEGF  (-1e30f)
#define LOG2E 1.4426950408889634f
#define LN2   0.6931471805599453f

__device__ __forceinline__ int   f2i(float x) { return __float_as_int(x); }
__device__ __forceinline__ float i2f(int x)   { return __int_as_float(x); }

// base-2 logaddexp (hardware-native: v_exp_f32/v_log_f32 are 2^x / log2)
__device__ __forceinline__ float lae2_2(float a, float b) {
  float m = fmaxf(a, b);
  float d = fminf(a, b) - m;          // 0 if both equal (incl. both NEGF)
  return m + __builtin_amdgcn_logf(1.0f + __builtin_amdgcn_exp2f(d));
}

// ---------- Phase 1: per-block partial sums of log-sum-exp over valid t ----------
// grid: B*16 blocks of 256 threads; block bid covers 64 t-rows of b = bid>>4.
// Writes partials[bid] (pure store, no init needed). Block 0 also zeroes out[0].
extern "C" __global__ void __launch_bounds__(256)
ctc_lse(const float* __restrict__ logits, const int* __restrict__ mask,
        float* __restrict__ partials, float* __restrict__ out) {
  const int bid = blockIdx.x;
  const int b   = bid >> 4;
  const int tb  = (bid & 15) << 6;
  const int tid = threadIdx.x;
  const int lane = tid & 63;
  const int w    = tid >> 6;

  if (bid == 0 && tid == 0) out[0] = 0.0f;   // d_out is re-poisoned before each call

  const float* lg = logits + (size_t)b * TT * VV;
  const int colv = (lane & 15) << 2;

  float acc = 0.0f;
#pragma unroll
  for (int p = 0; p < 4; ++p) {
    const int rowT = tb + (w << 4) + (p << 2) + (lane >> 4);
    const float4 v = *(const float4*)(lg + (size_t)rowT * VV + colv);
    float s = __expf(v.x) + __expf(v.y) + __expf(v.z) + __expf(v.w);
    s += __shfl_xor(s, 1);
    s += __shfl_xor(s, 2);
    s += __shfl_xor(s, 4);
    s += __shfl_xor(s, 8);             // 16-lane group sum -> row LSE argument
    if ((lane & 15) == 0) {
      const int mv = mask[b * TT + rowT];   // prefix-true: mv!=0 <=> t < len
      acc += mv ? __logf(s) : 0.0f;
    }
  }
  acc = ((lane & 15) == 0) ? acc : 0.0f;
  acc += __shfl_xor(acc, 16);
  acc += __shfl_xor(acc, 32);

  __shared__ float wsum[4];
  if (lane == 0) wsum[w] = acc;
  __syncthreads();
  if (tid == 0) partials[bid] = wsum[0] + wsum[1] + wsum[2] + wsum[3];
}

// ---------- Phase 2: sequential alpha DP on RAW logits, base-2 log space ----------
// One wave per b. Lane l holds alpha[2l] (a0), alpha[2l+1] (a1); lane63 also
// alpha[128] (a2). Prefetch ring = 32 NAMED scalars (xg0..15, xb0..15) with a
// macro-unrolled 16-step body: nothing for SROA to miss, guaranteed VGPRs.
extern "C" __global__ void __launch_bounds__(64)
ctc_dp(const int* __restrict__ labels, const float* __restrict__ logits,
       const int* __restrict__ mask, const float* __restrict__ partials,
       float* __restrict__ out) {
  const int b = blockIdx.x;
  const int lane = threadIdx.x;

  const int lab = labels[b * LL + lane];                 // label for state 2*lane+1
  const int lab_len = (int)__popcll(__ballot(lab != 0));

  // sum of per-block LSE partials for this b (16 slots)
  float psum = (lane < 16) ? partials[(b << 4) + lane] : 0.0f;
  psum += __shfl_xor(psum, 1);
  psum += __shfl_xor(psum, 2);
  psum += __shfl_xor(psum, 4);
  psum += __shfl_xor(psum, 8);
  const float sumLse = i2f(__builtin_amdgcn_readfirstlane(f2i(psum)));

  // logits_len = popcount of prefix-true mask row
  int lsum = 0;
  const int* mrow = mask + b * TT;
#pragma unroll
  for (int k = 0; k < TT / 64; ++k) lsum += mrow[lane + (k << 6)];
#pragma unroll
  for (int off = 32; off; off >>= 1) lsum += __shfl_xor(lsum, off);
  int len = __builtin_amdgcn_readfirstlane(lsum);
  len = len < 1 ? 1 : (len > TT ? TT : len);

  // allow_skip for odd state: lab != 0 && lab != prev lab
  const int plab = __builtin_amdgcn_update_dpp(0, lab, 0x138, 0xF, 0xF, false); // wave_shr:1
  const bool skip_ok = (lab != 0) && (lab != plab);

  const float* lg   = logits + (size_t)b * TT * VV;
  const float* glab = lg + (lab & 63);                   // per-lane gather base

  // prefetch ring: 32 named scalars, depth 16
  float xg0, xg1, xg2, xg3, xg4, xg5, xg6, xg7, xg8, xg9, xg10, xg11, xg12, xg13, xg14, xg15;
  float xb0, xb1, xb2, xb3, xb4, xb5, xb6, xb7, xb8, xb9, xb10, xb11, xb12, xb13, xb14, xb15;
#define RING_INIT(I) xg##I = glab[(I) * VV]; xb##I = lg[(I) * VV];
  RING_INIT(0)  RING_INIT(1)  RING_INIT(2)  RING_INIT(3)
  RING_INIT(4)  RING_INIT(5)  RING_INIT(6)  RING_INIT(7)
  RING_INIT(8)  RING_INIT(9)  RING_INIT(10) RING_INIT(11)
  RING_INIT(12) RING_INIT(13) RING_INIT(14) RING_INIT(15)
#undef RING_INIT

  float a0, a1, a2;   // base-2 log-space alpha

  // ---- t = 0 ----
  {
    a0 = (lane == 0) ? xb0 * LOG2E : NEGF;
    a1 = (lane == 0) ? xg0 * LOG2E : NEGF;
    a2 = NEGF;
    xg0 = glab[16 * VV];
    xb0 = lg[16 * VV];
  }

  // ---- t = 1 .. len-1, macro-unrolled 16-step blocks (freeze via cndmask) ----
#define STEP(U, SLOT) { \
    const int t = tb_ + (U); \
    const float x0s = xb##SLOT * LOG2E; \
    const float xls = xg##SLOT * LOG2E; \
    int pf = t + 16; pf = pf > (TT - 1) ? (TT - 1) : pf; \
    xg##SLOT = glab[(size_t)pf * VV]; \
    xb##SLOT = lg[(size_t)pf * VV]; \
    const float a1p = \
        i2f(__builtin_amdgcn_update_dpp(f2i(NEGF), f2i(a1), 0x138, 0xF, 0xF, false)); \
    const float m  = fmaxf(fmaxf(a0, a1), a1p); \
    const float E0 = __builtin_amdgcn_exp2f(a0 - m); \
    const float E1 = __builtin_amdgcn_exp2f(a1 - m); \
    const float Ep = __builtin_amdgcn_exp2f(a1p - m); \
    float na0 = x0s + m + __builtin_amdgcn_logf(E0 + Ep); \
    float na1 = xls + m + __builtin_amdgcn_logf(E0 + E1 + (skip_ok ? Ep : 0.0f)); \
    float na2 = x0s + lae2_2(a2, a1); \
    na0 = fmaxf(na0, NEGF); \
    na1 = fmaxf(na1, NEGF); \
    const bool act = t < len; \
    a0 = act ? na0 : a0; \
    a1 = act ? na1 : a1; \
    a2 = act ? na2 : a2; \
  }

  for (int tb_ = 1; tb_ < len; tb_ += 16) {
    STEP(0, 1)   STEP(1, 2)   STEP(2, 3)   STEP(3, 4)
    STEP(4, 5)   STEP(5, 6)   STEP(6, 7)   STEP(7, 8)
    STEP(8, 9)   STEP(9, 10)  STEP(10, 11) STEP(11, 12)
    STEP(12, 13) STEP(13, 14) STEP(14, 15) STEP(15, 0)
  }
#undef STEP

  // ---- epilogue: loss = sumLse - ln2 * lae2_2(alpha[e], alpha[e-1]), e = 2*lab_len ----
  float ae, ae1;
  if (lab_len >= LL) {            // e = 128
    ae  = i2f(__builtin_amdgcn_readlane(f2i(a2), 63));
    ae1 = i2f(__builtin_amdgcn_readlane(f2i(a1), 63));
  } else if (lab_len >= 1) {      // e = 2*lab_len
    ae  = i2f(__builtin_amdgcn_readlane(f2i(a0), lab_len));
    ae1 = i2f(__builtin_amdgcn_readlane(f2i(a1), lab_len - 1));
  } else {
    ae  = i2f(__builtin_amdgcn_readlane(f2i(a0), 0));
    ae1 = ae;
  }
  float loss = sumLse - LN2 * lae2_2(ae, ae1);
  if (lab_len > len) loss = 0.0f;  // feasibility mask
  if (lane == 0) atomicAdd(out, loss * (1.0f / 256.0f));
}

extern "C" void kernel_launch(void* const* d_in, const int* in_sizes, int n_in,
                              void* d_out, int out_size, void* d_ws, size_t ws_size,
                              hipStream_t stream) {
  (void)in_sizes; (void)n_in; (void)out_size; (void)ws_size;
  const int* labels = (const int*)d_in[0];
  const float* logits = (const float*)d_in[1];
  const int* mask = (const int*)d_in[2];
  float* partials = (float*)d_ws;   // BB*16 floats; fully overwritten each call

  ctc_lse<<<dim3(BB * (TT / 64)), dim3(256), 0, stream>>>(logits, mask, partials, (float*)d_out);
  ctc_dp<<<dim3(BB), dim3(64), 0, stream>>>(labels, logits, mask, partials, (float*)d_out);
}